// Round 4
// baseline (2081.358 us; speedup 1.0000x reference)
//
#include <hip/hip_runtime.h>
#include <hip/hip_bf16.h>
#include <type_traits>

typedef short bf16x8 __attribute__((ext_vector_type(8)));
typedef float f32x4 __attribute__((ext_vector_type(4)));

union PkAB { bf16x8 v; __hip_bfloat16 h[8]; };
union PkO  { uint2 u;  __hip_bfloat16 h[4]; };

#define NB_MAX 128      // max row-buckets (bucket = row >> 10)
#define EPB    2048     // edges per block in binning kernels

// ---------------- small utility kernels ----------------

__global__ __launch_bounds__(256) void zero_int_kernel(int* __restrict__ p, int n) {
    int i = blockIdx.x * blockDim.x + threadIdx.x;
    if (i < n) p[i] = 0;
}

// convert W1|W2|W3 (f32) to one contiguous bf16 array
__global__ __launch_bounds__(256) void convw_kernel(
    const float* __restrict__ W1, const float* __restrict__ W2,
    const float* __restrict__ W3, __hip_bfloat16* __restrict__ Wb,
    int n1, int n2, int n3)
{
    int i = (blockIdx.x * blockDim.x + threadIdx.x) * 4;
    if (i >= n1 + n2 + n3) return;
    const float* src; int off;
    if (i < n1)           { src = W1; off = i; }
    else if (i < n1 + n2) { src = W2; off = i - n1; }
    else                  { src = W3; off = i - n1 - n2; }
    const float4 v = *reinterpret_cast<const float4*>(src + off);
    PkO pk;
    pk.h[0] = __float2bfloat16(v.x); pk.h[1] = __float2bfloat16(v.y);
    pk.h[2] = __float2bfloat16(v.z); pk.h[3] = __float2bfloat16(v.w);
    *reinterpret_cast<uint2*>(Wb + i) = pk.u;
}

// ---------------- CSR build (binned, atomic-light) ----------------
// order: histB (bucket hist) -> scanB (bucket scan) -> bin_pass_a (bucket bin)
//        -> histr (per-bucket row hist from srow, LDS-only atomics)
//        -> scan (row scan) -> bin_pass_b (within-bucket scatter)

// bucket-only histogram: LDS 128 bins, 128 global atomics per block
__global__ __launch_bounds__(256) void histb_kernel(
    const int* __restrict__ erow, int* __restrict__ bcnt, int n_edges, int nb)
{
    __shared__ int lb[NB_MAX];
    const int tid = threadIdx.x;
    if (tid < NB_MAX) lb[tid] = 0;
    __syncthreads();
    const int e0 = blockIdx.x * EPB;
#pragma unroll
    for (int k = 0; k < 8; ++k) {
        const int e = e0 + tid + k * 256;
        if (e < n_edges) atomicAdd(&lb[erow[e] >> 10], 1);
    }
    __syncthreads();
    if (tid < nb && lb[tid]) atomicAdd(&bcnt[tid], lb[tid]);
}

// tiny bucket exclusive scan -> gcursor (for pass_a) + gstart (for histr)
__global__ __launch_bounds__(128) void scanb_kernel(
    const int* __restrict__ bcnt, int* __restrict__ gcursor,
    int* __restrict__ gstart, int nb, int n_edges)
{
    __shared__ int sb[NB_MAX];
    const int tid = threadIdx.x;
    if (tid < nb) sb[tid] = bcnt[tid];
    __syncthreads();
    if (tid == 0) {
        int run = 0;
        for (int b = 0; b < nb; ++b) { const int t = sb[b]; sb[b] = run; run += t; }
    }
    __syncthreads();
    if (tid < nb) { gcursor[tid] = sb[tid]; gstart[tid] = sb[tid]; }
    if (tid == 0) gstart[nb] = n_edges;
}

// pass A: bucket-bin edges; per-block contiguous range per bucket -> write-combinable
__global__ __launch_bounds__(256) void bin_pass_a(
    const int* __restrict__ erow, const int* __restrict__ ecol,
    const float* __restrict__ eval, int* __restrict__ gcursor,
    int* __restrict__ srow, uint2* __restrict__ epk8, int n_edges, int nb)
{
    __shared__ int cnt[NB_MAX];
    __shared__ int base_s[NB_MAX];
    __shared__ int lcur[NB_MAX];
    const int tid = threadIdx.x;
    if (tid < NB_MAX) { cnt[tid] = 0; lcur[tid] = 0; }
    __syncthreads();
    const int e0 = blockIdx.x * EPB;
    int r[8];
#pragma unroll
    for (int k = 0; k < 8; ++k) {
        const int e = e0 + tid + k * 256;
        r[k] = -1;
        if (e < n_edges) { r[k] = erow[e]; atomicAdd(&cnt[r[k] >> 10], 1); }
    }
    __syncthreads();
    if (tid < nb && cnt[tid] > 0) base_s[tid] = atomicAdd(&gcursor[tid], cnt[tid]);
    __syncthreads();
#pragma unroll
    for (int k = 0; k < 8; ++k) {
        const int e = e0 + tid + k * 256;
        if (e < n_edges) {
            const int b = r[k] >> 10;
            const int pos = base_s[b] + atomicAdd(&lcur[b], 1);
            srow[pos] = r[k];
            uint2 rec;
            rec.x = (unsigned)ecol[e];
            rec.y = __float_as_uint(eval[e]);
            epk8[pos] = rec;
        }
    }
}

// per-bucket row histogram from bucket-grouped srow; one block per bucket,
// LDS atomics only, plain stores (rows are bucket-exclusive, counts pre-zeroed)
__global__ __launch_bounds__(256) void histr_kernel(
    const int* __restrict__ gstart, const int* __restrict__ srow,
    int* __restrict__ counts, int n_nodes)
{
    __shared__ int h[1024];
    const int b = blockIdx.x;
    const int tid = threadIdx.x;
    for (int j = tid; j < 1024; j += 256) h[j] = 0;
    __syncthreads();
    const int lo = gstart[b], hi = gstart[b + 1];
    for (int i = lo + tid; i < hi; i += 256)
        atomicAdd(&h[srow[i] & 1023], 1);
    __syncthreads();
    const int rowbase = b << 10;
    for (int j = tid; j < 1024; j += 256) {
        const int r = rowbase + j;
        if (r < n_nodes && h[j]) counts[r] = h[j];
    }
}

// single-block scan: buckets -> gcursor ; rows -> row_ptr + cursor
__global__ __launch_bounds__(1024) void scan_kernel(
    const int* __restrict__ counts, const int* __restrict__ bcnt,
    int* __restrict__ row_ptr, int* __restrict__ cursor,
    int* __restrict__ gcursor, int n, int n_pad4, int nb)
{
    __shared__ int smem[1024];
    __shared__ int sb[NB_MAX];
    __shared__ int carry_s;
    const int tid = threadIdx.x;

    // bucket exclusive scan (small, serial in LDS)
    if (tid < nb) sb[tid] = bcnt[tid];
    if (tid == 0) carry_s = 0;
    __syncthreads();
    if (tid == 0) {
        int run = 0;
        for (int b = 0; b < nb; ++b) { const int t = sb[b]; sb[b] = run; run += t; }
    }
    __syncthreads();
    if (tid < nb) gcursor[tid] = sb[tid];
    __syncthreads();

    // row exclusive scan
    for (int base = 0; base < n_pad4; base += 4096) {
        const int i = base + tid * 4;
        int4 v = make_int4(0, 0, 0, 0);
        if (i < n_pad4) v = *reinterpret_cast<const int4*>(counts + i);
        const int s = v.x + v.y + v.z + v.w;
        smem[tid] = s;
        __syncthreads();
        for (int off = 1; off < 1024; off <<= 1) {
            int t = (tid >= off) ? smem[tid - off] : 0;
            __syncthreads();
            smem[tid] += t;
            __syncthreads();
        }
        const int incl = smem[tid];
        const int e0 = incl - s + carry_s;
        const int e1 = e0 + v.x;
        const int e2 = e1 + v.y;
        const int e3 = e2 + v.z;
        if (i     < n) { row_ptr[i]     = e0; cursor[i]     = e0; }
        if (i + 1 < n) { row_ptr[i + 1] = e1; cursor[i + 1] = e1; }
        if (i + 2 < n) { row_ptr[i + 2] = e2; cursor[i + 2] = e2; }
        if (i + 3 < n) { row_ptr[i + 3] = e3; cursor[i + 3] = e3; }
        __syncthreads();
        if (tid == 1023) carry_s += incl;
        __syncthreads();
    }
    if (tid == 0) row_ptr[n] = carry_s;
}

// pass B: within-bucket scatter to final CSR order (randomness confined to L2-sized region)
__global__ __launch_bounds__(256) void bin_pass_b(
    const int* __restrict__ srow, const uint2* __restrict__ epk8,
    int* __restrict__ cursor, uint2* __restrict__ epk, int n_edges)
{
    const int i = blockIdx.x * blockDim.x + threadIdx.x;
    if (i < n_edges) {
        const int r = srow[i];
        const int pos = atomicAdd(&cursor[r], 1);
        epk[pos] = epk8[i];
    }
}

// ---------------- MFMA GEMM: Y_bf16[M,N] = X[M,256] @ Wb[N,256]^T + b ----------------
// wave tile 64x64 (mt=4, nt=4). N==256: 4 waves span all cols (X read once, no
// cross-block A sharing). N==64: waves stack in M. A and B double-buffer-streamed.

template<typename TIN>
__device__ __forceinline__ bf16x8 load_frag(const TIN* __restrict__ p) {
    if constexpr (std::is_same<TIN, float>::value) {
        const float4 lo = *reinterpret_cast<const float4*>(p);
        const float4 hi = *reinterpret_cast<const float4*>(p + 4);
        PkAB pk;
        pk.h[0] = __float2bfloat16(lo.x); pk.h[1] = __float2bfloat16(lo.y);
        pk.h[2] = __float2bfloat16(lo.z); pk.h[3] = __float2bfloat16(lo.w);
        pk.h[4] = __float2bfloat16(hi.x); pk.h[5] = __float2bfloat16(hi.y);
        pk.h[6] = __float2bfloat16(hi.z); pk.h[7] = __float2bfloat16(hi.w);
        return pk.v;
    } else {
        return *reinterpret_cast<const bf16x8*>(p);
    }
}

template<typename TIN>
__global__ __launch_bounds__(256) void gemm_mfma_kernel(
    const TIN* __restrict__ X,
    const __hip_bfloat16* __restrict__ Wb,   // [N,256] bf16
    const float* __restrict__ bias,
    __hip_bfloat16* __restrict__ Y,
    int M, int N)
{
    constexpr int K = 256;
    const int tid  = threadIdx.x;
    const int lane = tid & 63;
    const int w    = tid >> 6;
    const int quad = lane >> 4;
    const int l16  = lane & 15;
    const bool wide = (N == 256);
    const int m0 = blockIdx.x * (wide ? 64 : 256) + (wide ? 0 : w * 64);
    const int n0 = wide ? w * 64 : 0;

    int mr[4];
#pragma unroll
    for (int mt = 0; mt < 4; ++mt) {
        const int r = m0 + mt * 16 + l16;
        mr[mt] = (r < M) ? r : (M - 1);   // clamped read; store guarded
    }
    const __hip_bfloat16* wp = Wb + (size_t)(n0 + l16) * K + quad * 8;

    f32x4 acc[4][4] = {};
    bf16x8 a_cur[4], b_cur[4];
#pragma unroll
    for (int mt = 0; mt < 4; ++mt)
        a_cur[mt] = load_frag(X + (size_t)mr[mt] * K + quad * 8);
#pragma unroll
    for (int nt = 0; nt < 4; ++nt)
        b_cur[nt] = *reinterpret_cast<const bf16x8*>(wp + nt * 16 * K);

#pragma unroll
    for (int ks = 0; ks < 8; ++ks) {
        bf16x8 a_nxt[4], b_nxt[4];
        if (ks < 7) {
            const int ko = (ks + 1) * 32 + quad * 8;
#pragma unroll
            for (int mt = 0; mt < 4; ++mt)
                a_nxt[mt] = load_frag(X + (size_t)mr[mt] * K + ko);
#pragma unroll
            for (int nt = 0; nt < 4; ++nt)
                b_nxt[nt] = *reinterpret_cast<const bf16x8*>(wp + nt * 16 * K + (ks + 1) * 32);
        }
#pragma unroll
        for (int mt = 0; mt < 4; ++mt)
#pragma unroll
            for (int nt = 0; nt < 4; ++nt)
                acc[mt][nt] = __builtin_amdgcn_mfma_f32_16x16x32_bf16(
                    a_cur[mt], b_cur[nt], acc[mt][nt], 0, 0, 0);
        if (ks < 7) {
#pragma unroll
            for (int mt = 0; mt < 4; ++mt) a_cur[mt] = a_nxt[mt];
#pragma unroll
            for (int nt = 0; nt < 4; ++nt) b_cur[nt] = b_nxt[nt];
        }
    }

    float bv[4];
#pragma unroll
    for (int nt = 0; nt < 4; ++nt) bv[nt] = bias[n0 + nt * 16 + l16];
#pragma unroll
    for (int mt = 0; mt < 4; ++mt)
#pragma unroll
        for (int r = 0; r < 4; ++r) {
            const int row = m0 + mt * 16 + quad * 4 + r;
            if (row < M) {
#pragma unroll
                for (int nt = 0; nt < 4; ++nt)
                    Y[(size_t)row * N + n0 + nt * 16 + l16] =
                        __float2bfloat16(acc[mt][nt][r] + bv[nt]);
            }
        }
}

// ---------------- CSR gather SpMM ----------------

// C=256 XCD-sliced pass: slice = blockIdx.x & 7 -> XCD (round-robin bid%8).
// Each XCD gathers only its 32-channel (64 B = 1 cache line) slice of H:
// 6.4 MB working set vs 4 MB per-XCD L2 -> high L2 hit rate, less fabric traffic.
// Wave: 4 edge-groups x 16 lanes; cross-group shfl reduction at row end.
template<bool RELU>
__global__ __launch_bounds__(256) void spmm_slice_kernel(
    const int* __restrict__ row_ptr,
    const uint2* __restrict__ epk,        // packed {col, val_bits}
    const unsigned int* __restrict__ H,   // bf16 pairs; row stride 128 uints
    unsigned int* __restrict__ out,       // bf16 pairs; row stride 128 uints
    int n_nodes)
{
    const int slice = blockIdx.x & 7;
    const int row   = (blockIdx.x >> 3) * 4 + (threadIdx.x >> 6);
    if (row >= n_nodes) return;
    const int lane = threadIdx.x & 63;
    const int sub  = lane >> 4;          // edge sub-group 0..3
    const int c16  = lane & 15;          // channel-pair within slice
    const unsigned int* Hs = H + slice * 16 + c16;
    const unsigned long long* ep8 = reinterpret_cast<const unsigned long long*>(epk);

    const int pbeg = row_ptr[row];
    const int end  = row_ptr[row + 1];

    float a0 = 0.f, a1 = 0.f;
    union { unsigned int i; float f; } t;

#define ACC_E(u, vbits)                                                     \
    t.i = (u) << 16;          a0 = fmaf(__uint_as_float(vbits), t.f, a0);   \
    t.i = (u) & 0xffff0000u;  a1 = fmaf(__uint_as_float(vbits), t.f, a1);

    int p = pbeg;
    for (; p + 7 < end; p += 8) {
        const unsigned long long e0 = __builtin_nontemporal_load(ep8 + p + sub);
        const unsigned long long e1 = __builtin_nontemporal_load(ep8 + p + sub + 4);
        const unsigned int u0 = Hs[(size_t)(unsigned)e0 * 128];
        const unsigned int u1 = Hs[(size_t)(unsigned)e1 * 128];
        ACC_E(u0, (unsigned)(e0 >> 32))
        ACC_E(u1, (unsigned)(e1 >> 32))
    }
    for (p += sub; p < end; p += 4) {
        const unsigned long long e = __builtin_nontemporal_load(ep8 + p);
        const unsigned int u = Hs[(size_t)(unsigned)e * 128];
        ACC_E(u, (unsigned)(e >> 32))
    }
#undef ACC_E

    a0 += __shfl_down(a0, 32, 64);  a1 += __shfl_down(a1, 32, 64);
    a0 += __shfl_down(a0, 16, 64);  a1 += __shfl_down(a1, 16, 64);
    if (sub == 0) {
        if (RELU) { a0 = fmaxf(a0, 0.f); a1 = fmaxf(a1, 0.f); }
        union { unsigned int u; __hip_bfloat16 h[2]; } o;
        o.h[0] = __float2bfloat16(a0); o.h[1] = __float2bfloat16(a1);
        __builtin_nontemporal_store(o.u, &out[(size_t)row * 128 + slice * 16 + c16]);
    }
}

// C=64: one wave per row; half-wave per edge (lane = 2 channels); f32 out
__global__ __launch_bounds__(256) void spmm_csr64_kernel(
    const int* __restrict__ row_ptr,
    const uint2* __restrict__ epk,
    const __hip_bfloat16* __restrict__ H,  // row stride 64
    float* __restrict__ out, int n_nodes)
{
    const int row = blockIdx.x * 4 + (threadIdx.x >> 6);
    if (row >= n_nodes) return;
    const int lane = threadIdx.x & 63;
    const int half = lane >> 5;
    const int sl   = lane & 31;

    const int end = row_ptr[row + 1];
    int p = row_ptr[row] + half;

    float a0 = 0.f, a1 = 0.f;
    union { unsigned int i; float f; } t;

#define ACC_E64(u, v)                                    \
    t.i = (u) << 16;          a0 = fmaf((v), t.f, a0);   \
    t.i = (u) & 0xffff0000u;  a1 = fmaf((v), t.f, a1);

    for (; p + 6 < end; p += 8) {   // this half handles p, p+2, p+4, p+6
        uint2 r[4];
#pragma unroll
        for (int j = 0; j < 4; ++j) r[j] = epk[p + 2 * j];
        unsigned int u[4];
#pragma unroll
        for (int j = 0; j < 4; ++j)
            u[j] = *reinterpret_cast<const unsigned int*>(H + (size_t)r[j].x * 64 + sl * 2);
#pragma unroll
        for (int j = 0; j < 4; ++j) { ACC_E64(u[j], __uint_as_float(r[j].y)) }
    }
    for (; p < end; p += 2) {
        const uint2 r = epk[p];
        const unsigned int u = *reinterpret_cast<const unsigned int*>(H + (size_t)r.x * 64 + sl * 2);
        ACC_E64(u, __uint_as_float(r.y))
    }
#undef ACC_E64

    a0 += __shfl_down(a0, 32, 64);
    a1 += __shfl_down(a1, 32, 64);
    if (half == 0)
        *reinterpret_cast<float2*>(out + (size_t)row * 64 + sl * 2) = make_float2(a0, a1);
}

// ---------------- launch ----------------

extern "C" void kernel_launch(void* const* d_in, const int* in_sizes, int n_in,
                              void* d_out, int out_size, void* d_ws, size_t ws_size,
                              hipStream_t stream)
{
    const float* x    = (const float*)d_in[0];
    const int*   erow = (const int*)  d_in[1];
    const int*   ecol = (const int*)  d_in[2];
    const float* eval = (const float*)d_in[3];
    const float* W1   = (const float*)d_in[4];
    const float* b1   = (const float*)d_in[5];
    const float* W2   = (const float*)d_in[6];
    const float* b2   = (const float*)d_in[7];
    const float* W3   = (const float*)d_in[8];
    const float* b3   = (const float*)d_in[9];
    float* out = (float*)d_out;

    const int IN_C = 256, HID_C = 256, OUT_C = 64;
    const int n_nodes = in_sizes[0] / IN_C;
    const int n_edges = in_sizes[1];
    const int n_pad4  = (n_nodes + 3) & ~3;
    const int nb      = (n_nodes + 1023) >> 10;   // row buckets (<= NB_MAX)

    // workspace (~168 MB), all chunks 16B-aligned
    char* wsp = (char*)d_ws;
    auto take = [&wsp](size_t bytes) {
        char* p = wsp;
        wsp += (bytes + 15) & ~(size_t)15;
        return p;
    };
    __hip_bfloat16* G  = (__hip_bfloat16*)take((size_t)n_nodes * HID_C * 2);
    __hip_bfloat16* H  = (__hip_bfloat16*)take((size_t)n_nodes * HID_C * 2);
    uint2* epk    = (uint2*)take((size_t)n_edges * 8);
    int*   srow   = (int*)take((size_t)n_edges * 4);
    uint2* epk8   = (uint2*)take((size_t)n_edges * 8);
    int*   counts = (int*)take((size_t)(n_pad4 + NB_MAX) * 4);  // counts + bcnt contiguous
    int*   bcnt   = counts + n_pad4;
    int*   gcursor= (int*)take((size_t)NB_MAX * 4);
    int*   gstart = (int*)take((size_t)(NB_MAX + 1) * 4);
    int*   cursor = (int*)take((size_t)n_pad4 * 4);
    int*   row_ptr= (int*)take((size_t)(n_nodes + 1) * 4);
    __hip_bfloat16* Wb1 = (__hip_bfloat16*)take((size_t)(HID_C * IN_C + HID_C * HID_C + OUT_C * HID_C) * 2);
    __hip_bfloat16* Wb2 = Wb1 + HID_C * IN_C;
    __hip_bfloat16* Wb3 = Wb2 + HID_C * HID_C;

    const dim3 blk(256);
    const int n1 = HID_C * IN_C, n2 = HID_C * HID_C, n3 = OUT_C * HID_C;
    const int cwb = ((n1 + n2 + n3) / 4 + 255) / 256;
    const int zb  = (n_pad4 + NB_MAX + 255) / 256;
    const int ebb = (n_edges + EPB - 1) / EPB;
    const int pbb = (n_edges + 255) / 256;
    const int rb  = (n_nodes + 3) / 4;            // spmm: 4 rows (waves) per block
    const int rs  = ((n_nodes + 3) / 4) * 8;      // sliced spmm: 8 slices
    const int g_w = (n_nodes + 63) / 64;          // wide GEMM grid
    const int g_n = (n_nodes + 255) / 256;        // narrow GEMM grid

    // ---- weight convert + CSR build ----
    convw_kernel<<<cwb, blk, 0, stream>>>(W1, W2, W3, Wb1, n1, n2, n3);
    zero_int_kernel<<<zb, blk, 0, stream>>>(counts, n_pad4 + NB_MAX);
    histb_kernel<<<ebb, blk, 0, stream>>>(erow, bcnt, n_edges, nb);
    scanb_kernel<<<1, 128, 0, stream>>>(bcnt, gcursor, gstart, nb, n_edges);
    bin_pass_a<<<ebb, blk, 0, stream>>>(erow, ecol, eval, gcursor, srow, epk8, n_edges, nb);
    histr_kernel<<<nb, blk, 0, stream>>>(gstart, srow, counts, n_nodes);
    scan_kernel<<<1, 1024, 0, stream>>>(counts, bcnt, row_ptr, cursor, gcursor,
                                        n_nodes, n_pad4, nb);
    bin_pass_b<<<pbb, blk, 0, stream>>>(srow, epk8, cursor, epk, n_edges);

    // Layer 1: G = x @ W1^T + b1 ; H = relu(spmm(G))
    gemm_mfma_kernel<float><<<g_w, blk, 0, stream>>>(x, Wb1, b1, G, n_nodes, HID_C);
    spmm_slice_kernel<true><<<rs, blk, 0, stream>>>(row_ptr, epk,
        (const unsigned int*)G, (unsigned int*)H, n_nodes);

    // Layer 2: G = H @ W2^T + b2 ; H = relu(spmm(G))
    gemm_mfma_kernel<__hip_bfloat16><<<g_w, blk, 0, stream>>>(H, Wb2, b2, G, n_nodes, HID_C);
    spmm_slice_kernel<true><<<rs, blk, 0, stream>>>(row_ptr, epk,
        (const unsigned int*)G, (unsigned int*)H, n_nodes);

    // Layer 3: G[:, :64] = H @ W3^T + b3 ; out = spmm(G)
    gemm_mfma_kernel<__hip_bfloat16><<<g_n, blk, 0, stream>>>(H, Wb3, b3, G, n_nodes, OUT_C);
    spmm_csr64_kernel<<<rb, blk, 0, stream>>>(row_ptr, epk, G, out, n_nodes);
}

// Round 5
// 1113.590 us; speedup vs baseline: 1.8691x; 1.8691x over previous
//
#include <hip/hip_runtime.h>
#include <hip/hip_bf16.h>
#include <type_traits>

typedef short bf16x8 __attribute__((ext_vector_type(8)));
typedef float f32x4 __attribute__((ext_vector_type(4)));

union PkAB { bf16x8 v; __hip_bfloat16 h[8]; };
union PkO  { uint2 u;  __hip_bfloat16 h[4]; };

#define NB_SHIFT 9      // bucket = row >> 9 (512 rows/bucket)
#define NB_ROWS  512
#define NB_MAX   256    // max row-buckets
#define EPB      2048   // edges per block in binning kernels

// ---------------- small utility kernels ----------------

__global__ __launch_bounds__(256) void zero_int_kernel(int* __restrict__ p, int n) {
    int i = blockIdx.x * blockDim.x + threadIdx.x;
    if (i < n) p[i] = 0;
}

// convert W1|W2|W3 (f32) to one contiguous bf16 array
__global__ __launch_bounds__(256) void convw_kernel(
    const float* __restrict__ W1, const float* __restrict__ W2,
    const float* __restrict__ W3, __hip_bfloat16* __restrict__ Wb,
    int n1, int n2, int n3)
{
    int i = (blockIdx.x * blockDim.x + threadIdx.x) * 4;
    if (i >= n1 + n2 + n3) return;
    const float* src; int off;
    if (i < n1)           { src = W1; off = i; }
    else if (i < n1 + n2) { src = W2; off = i - n1; }
    else                  { src = W3; off = i - n1 - n2; }
    const float4 v = *reinterpret_cast<const float4*>(src + off);
    PkO pk;
    pk.h[0] = __float2bfloat16(v.x); pk.h[1] = __float2bfloat16(v.y);
    pk.h[2] = __float2bfloat16(v.z); pk.h[3] = __float2bfloat16(v.w);
    *reinterpret_cast<uint2*>(Wb + i) = pk.u;
}

// ---------------- CSR build (binned, atomic-light) ----------------
// histb (bucket hist, LDS) -> scanb (bucket scan) -> bin_pass_a (bucket bin)
// -> histr (per-bucket row hist, LDS atomics, plain stores)
// -> scan (row exclusive scan -> row_ptr)
// -> bin_pass_b2 (per-bucket scatter, LDS cursor -> NO global atomics)

__global__ __launch_bounds__(256) void histb_kernel(
    const int* __restrict__ erow, int* __restrict__ bcnt, int n_edges, int nb)
{
    __shared__ int lb[NB_MAX];
    const int tid = threadIdx.x;
    if (tid < NB_MAX) lb[tid] = 0;
    __syncthreads();
    const int e0 = blockIdx.x * EPB;
#pragma unroll
    for (int k = 0; k < 8; ++k) {
        const int e = e0 + tid + k * 256;
        if (e < n_edges) atomicAdd(&lb[erow[e] >> NB_SHIFT], 1);
    }
    __syncthreads();
    if (tid < nb && lb[tid]) atomicAdd(&bcnt[tid], lb[tid]);
}

// tiny bucket exclusive scan -> gcursor (pass_a alloc) + gstart (bucket ranges)
__global__ __launch_bounds__(256) void scanb_kernel(
    const int* __restrict__ bcnt, int* __restrict__ gcursor,
    int* __restrict__ gstart, int nb, int n_edges)
{
    __shared__ int sb[NB_MAX];
    const int tid = threadIdx.x;
    if (tid < nb) sb[tid] = bcnt[tid];
    __syncthreads();
    if (tid == 0) {
        int run = 0;
        for (int b = 0; b < nb; ++b) { const int t = sb[b]; sb[b] = run; run += t; }
    }
    __syncthreads();
    if (tid < nb) { gcursor[tid] = sb[tid]; gstart[tid] = sb[tid]; }
    if (tid == 0) gstart[nb] = n_edges;
}

// pass A: bucket-bin edges; per-block contiguous range per bucket
__global__ __launch_bounds__(256) void bin_pass_a(
    const int* __restrict__ erow, const int* __restrict__ ecol,
    const float* __restrict__ eval, int* __restrict__ gcursor,
    int* __restrict__ srow, uint2* __restrict__ epk8, int n_edges, int nb)
{
    __shared__ int cnt[NB_MAX];
    __shared__ int base_s[NB_MAX];
    __shared__ int lcur[NB_MAX];
    const int tid = threadIdx.x;
    if (tid < NB_MAX) { cnt[tid] = 0; lcur[tid] = 0; }
    __syncthreads();
    const int e0 = blockIdx.x * EPB;
    int r[8];
#pragma unroll
    for (int k = 0; k < 8; ++k) {
        const int e = e0 + tid + k * 256;
        r[k] = -1;
        if (e < n_edges) { r[k] = erow[e]; atomicAdd(&cnt[r[k] >> NB_SHIFT], 1); }
    }
    __syncthreads();
    if (tid < nb && cnt[tid] > 0) base_s[tid] = atomicAdd(&gcursor[tid], cnt[tid]);
    __syncthreads();
#pragma unroll
    for (int k = 0; k < 8; ++k) {
        const int e = e0 + tid + k * 256;
        if (e < n_edges) {
            const int b = r[k] >> NB_SHIFT;
            const int pos = base_s[b] + atomicAdd(&lcur[b], 1);
            srow[pos] = r[k];
            uint2 rec;
            rec.x = (unsigned)ecol[e];
            rec.y = __float_as_uint(eval[e]);
            epk8[pos] = rec;
        }
    }
}

// per-bucket row histogram from bucket-grouped srow (LDS atomics, plain stores)
__global__ __launch_bounds__(256) void histr_kernel(
    const int* __restrict__ gstart, const int* __restrict__ srow,
    int* __restrict__ counts, int n_nodes)
{
    __shared__ int h[NB_ROWS];
    const int b = blockIdx.x;
    const int tid = threadIdx.x;
    for (int j = tid; j < NB_ROWS; j += 256) h[j] = 0;
    __syncthreads();
    const int lo = gstart[b], hi = gstart[b + 1];
    for (int i = lo + tid; i < hi; i += 256)
        atomicAdd(&h[srow[i] & (NB_ROWS - 1)], 1);
    __syncthreads();
    const int rowbase = b << NB_SHIFT;
    for (int j = tid; j < NB_ROWS; j += 256) {
        const int r = rowbase + j;
        if (r < n_nodes && h[j]) counts[r] = h[j];
    }
}

// single-block row exclusive scan -> row_ptr
__global__ __launch_bounds__(1024) void scan_kernel(
    const int* __restrict__ counts, int* __restrict__ row_ptr,
    int n, int n_pad4)
{
    __shared__ int smem[1024];
    __shared__ int carry_s;
    const int tid = threadIdx.x;
    if (tid == 0) carry_s = 0;
    __syncthreads();

    for (int base = 0; base < n_pad4; base += 4096) {
        const int i = base + tid * 4;
        int4 v = make_int4(0, 0, 0, 0);
        if (i < n_pad4) v = *reinterpret_cast<const int4*>(counts + i);
        const int s = v.x + v.y + v.z + v.w;
        smem[tid] = s;
        __syncthreads();
        for (int off = 1; off < 1024; off <<= 1) {
            int t = (tid >= off) ? smem[tid - off] : 0;
            __syncthreads();
            smem[tid] += t;
            __syncthreads();
        }
        const int incl = smem[tid];
        const int e0 = incl - s + carry_s;
        const int e1 = e0 + v.x;
        const int e2 = e1 + v.y;
        const int e3 = e2 + v.z;
        if (i     < n) row_ptr[i]     = e0;
        if (i + 1 < n) row_ptr[i + 1] = e1;
        if (i + 2 < n) row_ptr[i + 2] = e2;
        if (i + 3 < n) row_ptr[i + 3] = e3;
        __syncthreads();
        if (tid == 1023) carry_s += incl;
        __syncthreads();
    }
    if (tid == 0) row_ptr[n] = carry_s;
}

// pass B2: one block per bucket; cursor in LDS (rows bucket-exclusive) ->
// zero global atomics; scatter confined to the bucket's ~130 KB epk range.
__global__ __launch_bounds__(256) void bin_pass_b2(
    const int* __restrict__ gstart, const int* __restrict__ srow,
    const uint2* __restrict__ epk8, const int* __restrict__ row_ptr,
    uint2* __restrict__ epk, int n_nodes)
{
    __shared__ int cur[NB_ROWS];
    const int b = blockIdx.x;
    const int tid = threadIdx.x;
    const int rowbase = b << NB_SHIFT;
    for (int j = tid; j < NB_ROWS; j += 256) {
        const int r = rowbase + j;
        cur[j] = (r < n_nodes) ? row_ptr[r] : 0;
    }
    __syncthreads();
    const int lo = gstart[b], hi = gstart[b + 1];
    int i = lo + tid;
    for (; i + 768 < hi; i += 1024) {
        const int r0 = srow[i];
        const int r1 = srow[i + 256];
        const int r2 = srow[i + 512];
        const int r3 = srow[i + 768];
        const uint2 e0 = epk8[i];
        const uint2 e1 = epk8[i + 256];
        const uint2 e2 = epk8[i + 512];
        const uint2 e3 = epk8[i + 768];
        epk[atomicAdd(&cur[r0 & (NB_ROWS - 1)], 1)] = e0;
        epk[atomicAdd(&cur[r1 & (NB_ROWS - 1)], 1)] = e1;
        epk[atomicAdd(&cur[r2 & (NB_ROWS - 1)], 1)] = e2;
        epk[atomicAdd(&cur[r3 & (NB_ROWS - 1)], 1)] = e3;
    }
    for (; i < hi; i += 256) {
        const int r = srow[i];
        epk[atomicAdd(&cur[r & (NB_ROWS - 1)], 1)] = epk8[i];
    }
}

// ---------------- MFMA GEMM: Y_bf16[M,N] = X[M,256] @ Wb[N,256]^T + b ----------------

template<typename TIN>
__device__ __forceinline__ bf16x8 load_frag(const TIN* __restrict__ p) {
    if constexpr (std::is_same<TIN, float>::value) {
        const float4 lo = *reinterpret_cast<const float4*>(p);
        const float4 hi = *reinterpret_cast<const float4*>(p + 4);
        PkAB pk;
        pk.h[0] = __float2bfloat16(lo.x); pk.h[1] = __float2bfloat16(lo.y);
        pk.h[2] = __float2bfloat16(lo.z); pk.h[3] = __float2bfloat16(lo.w);
        pk.h[4] = __float2bfloat16(hi.x); pk.h[5] = __float2bfloat16(hi.y);
        pk.h[6] = __float2bfloat16(hi.z); pk.h[7] = __float2bfloat16(hi.w);
        return pk.v;
    } else {
        return *reinterpret_cast<const bf16x8*>(p);
    }
}

template<typename TIN>
__global__ __launch_bounds__(256) void gemm_mfma_kernel(
    const TIN* __restrict__ X,
    const __hip_bfloat16* __restrict__ Wb,   // [N,256] bf16
    const float* __restrict__ bias,
    __hip_bfloat16* __restrict__ Y,
    int M, int N)
{
    constexpr int K = 256;
    const int tid  = threadIdx.x;
    const int lane = tid & 63;
    const int w    = tid >> 6;
    const int quad = lane >> 4;
    const int l16  = lane & 15;
    const bool wide = (N == 256);
    const int m0 = blockIdx.x * (wide ? 64 : 256) + (wide ? 0 : w * 64);
    const int n0 = wide ? w * 64 : 0;

    int mr[4];
#pragma unroll
    for (int mt = 0; mt < 4; ++mt) {
        const int r = m0 + mt * 16 + l16;
        mr[mt] = (r < M) ? r : (M - 1);   // clamped read; store guarded
    }
    const __hip_bfloat16* wp = Wb + (size_t)(n0 + l16) * K + quad * 8;

    f32x4 acc[4][4] = {};
    bf16x8 a_cur[4], b_cur[4];
#pragma unroll
    for (int mt = 0; mt < 4; ++mt)
        a_cur[mt] = load_frag(X + (size_t)mr[mt] * K + quad * 8);
#pragma unroll
    for (int nt = 0; nt < 4; ++nt)
        b_cur[nt] = *reinterpret_cast<const bf16x8*>(wp + nt * 16 * K);

#pragma unroll
    for (int ks = 0; ks < 8; ++ks) {
        bf16x8 a_nxt[4], b_nxt[4];
        if (ks < 7) {
            const int ko = (ks + 1) * 32 + quad * 8;
#pragma unroll
            for (int mt = 0; mt < 4; ++mt)
                a_nxt[mt] = load_frag(X + (size_t)mr[mt] * K + ko);
#pragma unroll
            for (int nt = 0; nt < 4; ++nt)
                b_nxt[nt] = *reinterpret_cast<const bf16x8*>(wp + nt * 16 * K + (ks + 1) * 32);
        }
#pragma unroll
        for (int mt = 0; mt < 4; ++mt)
#pragma unroll
            for (int nt = 0; nt < 4; ++nt)
                acc[mt][nt] = __builtin_amdgcn_mfma_f32_16x16x32_bf16(
                    a_cur[mt], b_cur[nt], acc[mt][nt], 0, 0, 0);
        if (ks < 7) {
#pragma unroll
            for (int mt = 0; mt < 4; ++mt) a_cur[mt] = a_nxt[mt];
#pragma unroll
            for (int nt = 0; nt < 4; ++nt) b_cur[nt] = b_nxt[nt];
        }
    }

    float bv[4];
#pragma unroll
    for (int nt = 0; nt < 4; ++nt) bv[nt] = bias[n0 + nt * 16 + l16];
#pragma unroll
    for (int mt = 0; mt < 4; ++mt)
#pragma unroll
        for (int r = 0; r < 4; ++r) {
            const int row = m0 + mt * 16 + quad * 4 + r;
            if (row < M) {
#pragma unroll
                for (int nt = 0; nt < 4; ++nt)
                    Y[(size_t)row * N + n0 + nt * 16 + l16] =
                        __float2bfloat16(acc[mt][nt][r] + bv[nt]);
            }
        }
}

// ---------------- CSR gather SpMM ----------------

// C=256: one wave per row, lane = 4 channels; 8 edges in flight; bf16 out (+relu).
// This form is at the fabric/delivered-bytes roofline (~7.9 TB/s, 217 us).
template<bool RELU>
__global__ __launch_bounds__(256) void spmm_csr256_kernel(
    const int* __restrict__ row_ptr,
    const uint2* __restrict__ epk,        // packed {col, val_bits}
    const unsigned int* __restrict__ H,   // bf16 pairs; row stride 128 uints
    __hip_bfloat16* __restrict__ out,     // row stride 256
    int n_nodes)
{
    const int row = blockIdx.x * 4 + (threadIdx.x >> 6);
    if (row >= n_nodes) return;
    const int lane = threadIdx.x & 63;
    const int cu = lane * 2;

    int p = row_ptr[row];
    const int end = row_ptr[row + 1];

    float a0 = 0.f, a1 = 0.f, a2 = 0.f, a3 = 0.f;
    union { unsigned int i; float f; } t;

#define ACC_EDGE(u, v)                                        \
    t.i = (u).x << 16;          a0 = fmaf((v), t.f, a0);      \
    t.i = (u).x & 0xffff0000u;  a1 = fmaf((v), t.f, a1);      \
    t.i = (u).y << 16;          a2 = fmaf((v), t.f, a2);      \
    t.i = (u).y & 0xffff0000u;  a3 = fmaf((v), t.f, a3);

    for (; p + 7 < end; p += 8) {
        uint2 r[8];
#pragma unroll
        for (int j = 0; j < 8; ++j) r[j] = epk[p + j];
        uint2 u[8];
#pragma unroll
        for (int j = 0; j < 8; ++j)
            u[j] = *reinterpret_cast<const uint2*>(H + (size_t)r[j].x * 128 + cu);
#pragma unroll
        for (int j = 0; j < 8; ++j) { ACC_EDGE(u[j], __uint_as_float(r[j].y)) }
    }
    for (; p < end; ++p) {
        const uint2 r = epk[p];
        const uint2 u = *reinterpret_cast<const uint2*>(H + (size_t)r.x * 128 + cu);
        ACC_EDGE(u, __uint_as_float(r.y))
    }
#undef ACC_EDGE

    if (RELU) {
        a0 = fmaxf(a0, 0.f); a1 = fmaxf(a1, 0.f);
        a2 = fmaxf(a2, 0.f); a3 = fmaxf(a3, 0.f);
    }
    PkO pk;
    pk.h[0] = __float2bfloat16(a0); pk.h[1] = __float2bfloat16(a1);
    pk.h[2] = __float2bfloat16(a2); pk.h[3] = __float2bfloat16(a3);
    *reinterpret_cast<uint2*>(out + (size_t)row * 256 + lane * 4) = pk.u;
}

// C=64: one wave per row; half-wave per edge (lane = 2 channels); f32 out
__global__ __launch_bounds__(256) void spmm_csr64_kernel(
    const int* __restrict__ row_ptr,
    const uint2* __restrict__ epk,
    const __hip_bfloat16* __restrict__ H,  // row stride 64
    float* __restrict__ out, int n_nodes)
{
    const int row = blockIdx.x * 4 + (threadIdx.x >> 6);
    if (row >= n_nodes) return;
    const int lane = threadIdx.x & 63;
    const int half = lane >> 5;
    const int sl   = lane & 31;

    const int end = row_ptr[row + 1];
    int p = row_ptr[row] + half;

    float a0 = 0.f, a1 = 0.f;
    union { unsigned int i; float f; } t;

#define ACC_E64(u, v)                                    \
    t.i = (u) << 16;          a0 = fmaf((v), t.f, a0);   \
    t.i = (u) & 0xffff0000u;  a1 = fmaf((v), t.f, a1);

    for (; p + 6 < end; p += 8) {   // this half handles p, p+2, p+4, p+6
        uint2 r[4];
#pragma unroll
        for (int j = 0; j < 4; ++j) r[j] = epk[p + 2 * j];
        unsigned int u[4];
#pragma unroll
        for (int j = 0; j < 4; ++j)
            u[j] = *reinterpret_cast<const unsigned int*>(H + (size_t)r[j].x * 64 + sl * 2);
#pragma unroll
        for (int j = 0; j < 4; ++j) { ACC_E64(u[j], __uint_as_float(r[j].y)) }
    }
    for (; p < end; p += 2) {
        const uint2 r = epk[p];
        const unsigned int u = *reinterpret_cast<const unsigned int*>(H + (size_t)r.x * 64 + sl * 2);
        ACC_E64(u, __uint_as_float(r.y))
    }
#undef ACC_E64

    a0 += __shfl_down(a0, 32, 64);
    a1 += __shfl_down(a1, 32, 64);
    if (half == 0)
        *reinterpret_cast<float2*>(out + (size_t)row * 64 + sl * 2) = make_float2(a0, a1);
}

// ---------------- launch ----------------

extern "C" void kernel_launch(void* const* d_in, const int* in_sizes, int n_in,
                              void* d_out, int out_size, void* d_ws, size_t ws_size,
                              hipStream_t stream)
{
    const float* x    = (const float*)d_in[0];
    const int*   erow = (const int*)  d_in[1];
    const int*   ecol = (const int*)  d_in[2];
    const float* eval = (const float*)d_in[3];
    const float* W1   = (const float*)d_in[4];
    const float* b1   = (const float*)d_in[5];
    const float* W2   = (const float*)d_in[6];
    const float* b2   = (const float*)d_in[7];
    const float* W3   = (const float*)d_in[8];
    const float* b3   = (const float*)d_in[9];
    float* out = (float*)d_out;

    const int IN_C = 256, HID_C = 256, OUT_C = 64;
    const int n_nodes = in_sizes[0] / IN_C;
    const int n_edges = in_sizes[1];
    const int n_pad4  = (n_nodes + 3) & ~3;
    const int nb      = (n_nodes + NB_ROWS - 1) >> NB_SHIFT;   // row buckets (<= NB_MAX)

    // workspace, all chunks 16B-aligned
    char* wsp = (char*)d_ws;
    auto take = [&wsp](size_t bytes) {
        char* p = wsp;
        wsp += (bytes + 15) & ~(size_t)15;
        return p;
    };
    __hip_bfloat16* G  = (__hip_bfloat16*)take((size_t)n_nodes * HID_C * 2);
    __hip_bfloat16* H  = (__hip_bfloat16*)take((size_t)n_nodes * HID_C * 2);
    uint2* epk    = (uint2*)take((size_t)n_edges * 8);
    int*   srow   = (int*)take((size_t)n_edges * 4);
    uint2* epk8   = (uint2*)take((size_t)n_edges * 8);
    int*   counts = (int*)take((size_t)(n_pad4 + NB_MAX) * 4);  // counts + bcnt contiguous
    int*   bcnt   = counts + n_pad4;
    int*   gcursor= (int*)take((size_t)NB_MAX * 4);
    int*   gstart = (int*)take((size_t)(NB_MAX + 1) * 4);
    int*   row_ptr= (int*)take((size_t)(n_nodes + 1) * 4);
    __hip_bfloat16* Wb1 = (__hip_bfloat16*)take((size_t)(HID_C * IN_C + HID_C * HID_C + OUT_C * HID_C) * 2);
    __hip_bfloat16* Wb2 = Wb1 + HID_C * IN_C;
    __hip_bfloat16* Wb3 = Wb2 + HID_C * HID_C;

    const dim3 blk(256);
    const int n1 = HID_C * IN_C, n2 = HID_C * HID_C, n3 = OUT_C * HID_C;
    const int cwb = ((n1 + n2 + n3) / 4 + 255) / 256;
    const int zb  = (n_pad4 + NB_MAX + 255) / 256;
    const int ebb = (n_edges + EPB - 1) / EPB;
    const int rb  = (n_nodes + 3) / 4;            // spmm: 4 rows (waves) per block
    const int g_w = (n_nodes + 63) / 64;          // wide GEMM grid
    const int g_n = (n_nodes + 255) / 256;        // narrow GEMM grid

    // ---- weight convert + CSR build ----
    convw_kernel<<<cwb, blk, 0, stream>>>(W1, W2, W3, Wb1, n1, n2, n3);
    zero_int_kernel<<<zb, blk, 0, stream>>>(counts, n_pad4 + NB_MAX);
    histb_kernel<<<ebb, blk, 0, stream>>>(erow, bcnt, n_edges, nb);
    scanb_kernel<<<1, 256, 0, stream>>>(bcnt, gcursor, gstart, nb, n_edges);
    bin_pass_a<<<ebb, blk, 0, stream>>>(erow, ecol, eval, gcursor, srow, epk8, n_edges, nb);
    histr_kernel<<<nb, blk, 0, stream>>>(gstart, srow, counts, n_nodes);
    scan_kernel<<<1, 1024, 0, stream>>>(counts, row_ptr, n_nodes, n_pad4);
    bin_pass_b2<<<nb, blk, 0, stream>>>(gstart, srow, epk8, row_ptr, epk, n_nodes);

    // Layer 1: G = x @ W1^T + b1 ; H = relu(spmm(G))
    gemm_mfma_kernel<float><<<g_w, blk, 0, stream>>>(x, Wb1, b1, G, n_nodes, HID_C);
    spmm_csr256_kernel<true><<<rb, blk, 0, stream>>>(row_ptr, epk,
                                                     (const unsigned int*)G, H, n_nodes);

    // Layer 2: G = H @ W2^T + b2 ; H = relu(spmm(G))
    gemm_mfma_kernel<__hip_bfloat16><<<g_w, blk, 0, stream>>>(H, Wb2, b2, G, n_nodes, HID_C);
    spmm_csr256_kernel<true><<<rb, blk, 0, stream>>>(row_ptr, epk,
                                                     (const unsigned int*)G, H, n_nodes);

    // Layer 3: G[:, :64] = H @ W3^T + b3 ; out = spmm(G)
    gemm_mfma_kernel<__hip_bfloat16><<<g_n, blk, 0, stream>>>(H, Wb3, b3, G, n_nodes, OUT_C);
    spmm_csr64_kernel<<<rb, blk, 0, stream>>>(row_ptr, epk, G, out, n_nodes);
}

// Round 6
// 1022.758 us; speedup vs baseline: 2.0350x; 1.0888x over previous
//
#include <hip/hip_runtime.h>
#include <hip/hip_bf16.h>
#include <type_traits>

typedef short bf16x8 __attribute__((ext_vector_type(8)));
typedef float f32x4 __attribute__((ext_vector_type(4)));

union PkAB { bf16x8 v; __hip_bfloat16 h[8]; };
union PkO  { uint2 u;  __hip_bfloat16 h[4]; };

#define NB_SHIFT 9      // bucket = row >> 9 (512 rows/bucket)
#define NB_ROWS  512
#define NB_MAX   256    // max row-buckets
#define EPB      8192   // edges per block in binning kernels (32/thread)

// ---------------- small utility kernels ----------------

__global__ __launch_bounds__(256) void zero_bcnt_kernel(int* __restrict__ p) {
    p[threadIdx.x] = 0;   // NB_MAX ints, one block
}

// convert W1|W2|W3 (f32) to one contiguous bf16 array
__global__ __launch_bounds__(256) void convw_kernel(
    const float* __restrict__ W1, const float* __restrict__ W2,
    const float* __restrict__ W3, __hip_bfloat16* __restrict__ Wb,
    int n1, int n2, int n3)
{
    int i = (blockIdx.x * blockDim.x + threadIdx.x) * 4;
    if (i >= n1 + n2 + n3) return;
    const float* src; int off;
    if (i < n1)           { src = W1; off = i; }
    else if (i < n1 + n2) { src = W2; off = i - n1; }
    else                  { src = W3; off = i - n1 - n2; }
    const float4 v = *reinterpret_cast<const float4*>(src + off);
    PkO pk;
    pk.h[0] = __float2bfloat16(v.x); pk.h[1] = __float2bfloat16(v.y);
    pk.h[2] = __float2bfloat16(v.z); pk.h[3] = __float2bfloat16(v.w);
    *reinterpret_cast<uint2*>(Wb + i) = pk.u;
}

// ---------------- CSR build (binned, atomic-light, no global row scan) ------
// histb (bucket hist, LDS) -> scanb (bucket scan -> gstart/gcursor)
// -> bin_pass_a (bucket bin) -> histr2 (per-bucket row hist + LDS scan ->
// row_ptr DIRECTLY; gstart[b] is the global prefix at the bucket boundary)
// -> bin_pass_b2 (per-bucket scatter, LDS cursor -> no global atomics)

__global__ __launch_bounds__(256) void histb_kernel(
    const int* __restrict__ erow, int* __restrict__ bcnt, int n_edges, int nb)
{
    __shared__ int lb[NB_MAX];
    const int tid = threadIdx.x;
    if (tid < NB_MAX) lb[tid] = 0;
    __syncthreads();
    const int e0 = blockIdx.x * EPB;
#pragma unroll
    for (int k = 0; k < 32; ++k) {
        const int e = e0 + tid + k * 256;
        if (e < n_edges) atomicAdd(&lb[erow[e] >> NB_SHIFT], 1);
    }
    __syncthreads();
    if (tid < nb && lb[tid]) atomicAdd(&bcnt[tid], lb[tid]);
}

// tiny bucket exclusive scan -> gcursor (pass_a alloc) + gstart (bucket ranges)
__global__ __launch_bounds__(256) void scanb_kernel(
    const int* __restrict__ bcnt, int* __restrict__ gcursor,
    int* __restrict__ gstart, int nb, int n_edges)
{
    __shared__ int sb[NB_MAX];
    const int tid = threadIdx.x;
    if (tid < nb) sb[tid] = bcnt[tid];
    __syncthreads();
    if (tid == 0) {
        int run = 0;
        for (int b = 0; b < nb; ++b) { const int t = sb[b]; sb[b] = run; run += t; }
    }
    __syncthreads();
    if (tid < nb) { gcursor[tid] = sb[tid]; gstart[tid] = sb[tid]; }
    if (tid == 0) gstart[nb] = n_edges;
}

// pass A: bucket-bin edges; per-block contiguous range per bucket.
// EPB=8192 -> ~42-edge runs per (block,bucket): near-full-line writes.
__global__ __launch_bounds__(256) void bin_pass_a(
    const int* __restrict__ erow, const int* __restrict__ ecol,
    const float* __restrict__ eval, int* __restrict__ gcursor,
    int* __restrict__ srow, uint2* __restrict__ epk8, int n_edges, int nb)
{
    __shared__ int cnt[NB_MAX];
    __shared__ int base_s[NB_MAX];
    __shared__ int lcur[NB_MAX];
    const int tid = threadIdx.x;
    if (tid < NB_MAX) { cnt[tid] = 0; lcur[tid] = 0; }
    __syncthreads();
    const int e0 = blockIdx.x * EPB;
    int r[32];
#pragma unroll
    for (int k = 0; k < 32; ++k) {
        const int e = e0 + tid + k * 256;
        r[k] = -1;
        if (e < n_edges) { r[k] = erow[e]; atomicAdd(&cnt[r[k] >> NB_SHIFT], 1); }
    }
    __syncthreads();
    if (tid < nb && cnt[tid] > 0) base_s[tid] = atomicAdd(&gcursor[tid], cnt[tid]);
    __syncthreads();
#pragma unroll
    for (int k = 0; k < 32; ++k) {
        const int e = e0 + tid + k * 256;
        if (e < n_edges) {
            const int b = r[k] >> NB_SHIFT;
            const int pos = base_s[b] + atomicAdd(&lcur[b], 1);
            srow[pos] = r[k];
            uint2 rec;
            rec.x = (unsigned)ecol[e];
            rec.y = __float_as_uint(eval[e]);
            epk8[pos] = rec;
        }
    }
}

// per-bucket row histogram + in-LDS exclusive scan -> row_ptr directly.
// gstart[b] (edges in buckets < b) is the global prefix at the bucket start,
// so no global row scan is needed.
__global__ __launch_bounds__(256) void histr2_kernel(
    const int* __restrict__ gstart, const int* __restrict__ srow,
    int* __restrict__ row_ptr, int n_nodes, int nb)
{
    __shared__ int h[NB_ROWS];
    __shared__ int hs[NB_ROWS];
    const int b = blockIdx.x;
    const int tid = threadIdx.x;
    h[tid] = 0; h[tid + 256] = 0;
    __syncthreads();
    const int lo = gstart[b], hi = gstart[b + 1];
    for (int i = lo + tid; i < hi; i += 256)
        atomicAdd(&h[srow[i] & (NB_ROWS - 1)], 1);
    __syncthreads();
    hs[tid] = h[tid]; hs[tid + 256] = h[tid + 256];
    __syncthreads();
    // inclusive Hillis-Steele over 512 entries (2 per thread; read-all-then-write)
    for (int off = 1; off < NB_ROWS; off <<= 1) {
        const int j0 = tid, j1 = tid + 256;
        const int a0 = (j0 >= off) ? hs[j0 - off] : 0;
        const int a1 = (j1 >= off) ? hs[j1 - off] : 0;
        __syncthreads();
        hs[j0] += a0; hs[j1] += a1;
        __syncthreads();
    }
    const int rowbase = b << NB_SHIFT;
#pragma unroll
    for (int s = 0; s < 2; ++s) {
        const int j = tid + s * 256;
        const int r = rowbase + j;
        if (r < n_nodes) row_ptr[r] = lo + hs[j] - h[j];   // exclusive
    }
    if (b == nb - 1 && tid == 0) row_ptr[n_nodes] = gstart[nb];
}

// pass B2: one block per bucket; cursor in LDS (rows bucket-exclusive) ->
// zero global atomics; scatter confined to the bucket's ~130 KB epk range.
__global__ __launch_bounds__(256) void bin_pass_b2(
    const int* __restrict__ gstart, const int* __restrict__ srow,
    const uint2* __restrict__ epk8, const int* __restrict__ row_ptr,
    uint2* __restrict__ epk, int n_nodes)
{
    __shared__ int cur[NB_ROWS];
    const int b = blockIdx.x;
    const int tid = threadIdx.x;
    const int rowbase = b << NB_SHIFT;
    for (int j = tid; j < NB_ROWS; j += 256) {
        const int r = rowbase + j;
        cur[j] = (r < n_nodes) ? row_ptr[r] : 0;
    }
    __syncthreads();
    const int lo = gstart[b], hi = gstart[b + 1];
    int i = lo + tid;
    for (; i + 768 < hi; i += 1024) {
        const int r0 = srow[i];
        const int r1 = srow[i + 256];
        const int r2 = srow[i + 512];
        const int r3 = srow[i + 768];
        const uint2 e0 = epk8[i];
        const uint2 e1 = epk8[i + 256];
        const uint2 e2 = epk8[i + 512];
        const uint2 e3 = epk8[i + 768];
        epk[atomicAdd(&cur[r0 & (NB_ROWS - 1)], 1)] = e0;
        epk[atomicAdd(&cur[r1 & (NB_ROWS - 1)], 1)] = e1;
        epk[atomicAdd(&cur[r2 & (NB_ROWS - 1)], 1)] = e2;
        epk[atomicAdd(&cur[r3 & (NB_ROWS - 1)], 1)] = e3;
    }
    for (; i < hi; i += 256) {
        const int r = srow[i];
        epk[atomicAdd(&cur[r & (NB_ROWS - 1)], 1)] = epk8[i];
    }
}

// ---------------- MFMA GEMM: Y_bf16[M,N] = X[M,256] @ Wb[N,256]^T + b ----------------

template<typename TIN>
__device__ __forceinline__ bf16x8 load_frag(const TIN* __restrict__ p) {
    if constexpr (std::is_same<TIN, float>::value) {
        const float4 lo = *reinterpret_cast<const float4*>(p);
        const float4 hi = *reinterpret_cast<const float4*>(p + 4);
        PkAB pk;
        pk.h[0] = __float2bfloat16(lo.x); pk.h[1] = __float2bfloat16(lo.y);
        pk.h[2] = __float2bfloat16(lo.z); pk.h[3] = __float2bfloat16(lo.w);
        pk.h[4] = __float2bfloat16(hi.x); pk.h[5] = __float2bfloat16(hi.y);
        pk.h[6] = __float2bfloat16(hi.z); pk.h[7] = __float2bfloat16(hi.w);
        return pk.v;
    } else {
        return *reinterpret_cast<const bf16x8*>(p);
    }
}

template<typename TIN>
__global__ __launch_bounds__(256) void gemm_mfma_kernel(
    const TIN* __restrict__ X,
    const __hip_bfloat16* __restrict__ Wb,   // [N,256] bf16
    const float* __restrict__ bias,
    __hip_bfloat16* __restrict__ Y,
    int M, int N)
{
    constexpr int K = 256;
    const int tid  = threadIdx.x;
    const int lane = tid & 63;
    const int w    = tid >> 6;
    const int quad = lane >> 4;
    const int l16  = lane & 15;
    const bool wide = (N == 256);
    const int m0 = blockIdx.x * (wide ? 64 : 256) + (wide ? 0 : w * 64);
    const int n0 = wide ? w * 64 : 0;

    int mr[4];
#pragma unroll
    for (int mt = 0; mt < 4; ++mt) {
        const int r = m0 + mt * 16 + l16;
        mr[mt] = (r < M) ? r : (M - 1);   // clamped read; store guarded
    }
    const __hip_bfloat16* wp = Wb + (size_t)(n0 + l16) * K + quad * 8;

    f32x4 acc[4][4] = {};
    bf16x8 a_cur[4], b_cur[4];
#pragma unroll
    for (int mt = 0; mt < 4; ++mt)
        a_cur[mt] = load_frag(X + (size_t)mr[mt] * K + quad * 8);
#pragma unroll
    for (int nt = 0; nt < 4; ++nt)
        b_cur[nt] = *reinterpret_cast<const bf16x8*>(wp + nt * 16 * K);

#pragma unroll
    for (int ks = 0; ks < 8; ++ks) {
        bf16x8 a_nxt[4], b_nxt[4];
        if (ks < 7) {
            const int ko = (ks + 1) * 32 + quad * 8;
#pragma unroll
            for (int mt = 0; mt < 4; ++mt)
                a_nxt[mt] = load_frag(X + (size_t)mr[mt] * K + ko);
#pragma unroll
            for (int nt = 0; nt < 4; ++nt)
                b_nxt[nt] = *reinterpret_cast<const bf16x8*>(wp + nt * 16 * K + (ks + 1) * 32);
        }
#pragma unroll
        for (int mt = 0; mt < 4; ++mt)
#pragma unroll
            for (int nt = 0; nt < 4; ++nt)
                acc[mt][nt] = __builtin_amdgcn_mfma_f32_16x16x32_bf16(
                    a_cur[mt], b_cur[nt], acc[mt][nt], 0, 0, 0);
        if (ks < 7) {
#pragma unroll
            for (int mt = 0; mt < 4; ++mt) a_cur[mt] = a_nxt[mt];
#pragma unroll
            for (int nt = 0; nt < 4; ++nt) b_cur[nt] = b_nxt[nt];
        }
    }

    float bv[4];
#pragma unroll
    for (int nt = 0; nt < 4; ++nt) bv[nt] = bias[n0 + nt * 16 + l16];
#pragma unroll
    for (int mt = 0; mt < 4; ++mt)
#pragma unroll
        for (int r = 0; r < 4; ++r) {
            const int row = m0 + mt * 16 + quad * 4 + r;
            if (row < M) {
#pragma unroll
                for (int nt = 0; nt < 4; ++nt)
                    Y[(size_t)row * N + n0 + nt * 16 + l16] =
                        __float2bfloat16(acc[mt][nt][r] + bv[nt]);
            }
        }
}

// ---------------- CSR gather SpMM ----------------

// C=256: one wave per row, lane = 4 channels; 8 edges in flight; bf16 out (+relu).
// At the fabric/delivered-bytes roofline (~7.9 TB/s, 217 us).
template<bool RELU>
__global__ __launch_bounds__(256) void spmm_csr256_kernel(
    const int* __restrict__ row_ptr,
    const uint2* __restrict__ epk,        // packed {col, val_bits}
    const unsigned int* __restrict__ H,   // bf16 pairs; row stride 128 uints
    __hip_bfloat16* __restrict__ out,     // row stride 256
    int n_nodes)
{
    const int row = blockIdx.x * 4 + (threadIdx.x >> 6);
    if (row >= n_nodes) return;
    const int lane = threadIdx.x & 63;
    const int cu = lane * 2;

    int p = row_ptr[row];
    const int end = row_ptr[row + 1];

    float a0 = 0.f, a1 = 0.f, a2 = 0.f, a3 = 0.f;
    union { unsigned int i; float f; } t;

#define ACC_EDGE(u, v)                                        \
    t.i = (u).x << 16;          a0 = fmaf((v), t.f, a0);      \
    t.i = (u).x & 0xffff0000u;  a1 = fmaf((v), t.f, a1);      \
    t.i = (u).y << 16;          a2 = fmaf((v), t.f, a2);      \
    t.i = (u).y & 0xffff0000u;  a3 = fmaf((v), t.f, a3);

    for (; p + 7 < end; p += 8) {
        uint2 r[8];
#pragma unroll
        for (int j = 0; j < 8; ++j) r[j] = epk[p + j];
        uint2 u[8];
#pragma unroll
        for (int j = 0; j < 8; ++j)
            u[j] = *reinterpret_cast<const uint2*>(H + (size_t)r[j].x * 128 + cu);
#pragma unroll
        for (int j = 0; j < 8; ++j) { ACC_EDGE(u[j], __uint_as_float(r[j].y)) }
    }
    for (; p < end; ++p) {
        const uint2 r = epk[p];
        const uint2 u = *reinterpret_cast<const uint2*>(H + (size_t)r.x * 128 + cu);
        ACC_EDGE(u, __uint_as_float(r.y))
    }
#undef ACC_EDGE

    if (RELU) {
        a0 = fmaxf(a0, 0.f); a1 = fmaxf(a1, 0.f);
        a2 = fmaxf(a2, 0.f); a3 = fmaxf(a3, 0.f);
    }
    PkO pk;
    pk.h[0] = __float2bfloat16(a0); pk.h[1] = __float2bfloat16(a1);
    pk.h[2] = __float2bfloat16(a2); pk.h[3] = __float2bfloat16(a3);
    *reinterpret_cast<uint2*>(out + (size_t)row * 256 + lane * 4) = pk.u;
}

// C=64: one wave per row; half-wave per edge (lane = 2 channels); f32 out
__global__ __launch_bounds__(256) void spmm_csr64_kernel(
    const int* __restrict__ row_ptr,
    const uint2* __restrict__ epk,
    const __hip_bfloat16* __restrict__ H,  // row stride 64
    float* __restrict__ out, int n_nodes)
{
    const int row = blockIdx.x * 4 + (threadIdx.x >> 6);
    if (row >= n_nodes) return;
    const int lane = threadIdx.x & 63;
    const int half = lane >> 5;
    const int sl   = lane & 31;

    const int end = row_ptr[row + 1];
    int p = row_ptr[row] + half;

    float a0 = 0.f, a1 = 0.f;
    union { unsigned int i; float f; } t;

#define ACC_E64(u, v)                                    \
    t.i = (u) << 16;          a0 = fmaf((v), t.f, a0);   \
    t.i = (u) & 0xffff0000u;  a1 = fmaf((v), t.f, a1);

    for (; p + 6 < end; p += 8) {   // this half handles p, p+2, p+4, p+6
        uint2 r[4];
#pragma unroll
        for (int j = 0; j < 4; ++j) r[j] = epk[p + 2 * j];
        unsigned int u[4];
#pragma unroll
        for (int j = 0; j < 4; ++j)
            u[j] = *reinterpret_cast<const unsigned int*>(H + (size_t)r[j].x * 64 + sl * 2);
#pragma unroll
        for (int j = 0; j < 4; ++j) { ACC_E64(u[j], __uint_as_float(r[j].y)) }
    }
    for (; p < end; p += 2) {
        const uint2 r = epk[p];
        const unsigned int u = *reinterpret_cast<const unsigned int*>(H + (size_t)r.x * 64 + sl * 2);
        ACC_E64(u, __uint_as_float(r.y))
    }
#undef ACC_E64

    a0 += __shfl_down(a0, 32, 64);
    a1 += __shfl_down(a1, 32, 64);
    if (half == 0)
        *reinterpret_cast<float2*>(out + (size_t)row * 64 + sl * 2) = make_float2(a0, a1);
}

// ---------------- launch ----------------

extern "C" void kernel_launch(void* const* d_in, const int* in_sizes, int n_in,
                              void* d_out, int out_size, void* d_ws, size_t ws_size,
                              hipStream_t stream)
{
    const float* x    = (const float*)d_in[0];
    const int*   erow = (const int*)  d_in[1];
    const int*   ecol = (const int*)  d_in[2];
    const float* eval = (const float*)d_in[3];
    const float* W1   = (const float*)d_in[4];
    const float* b1   = (const float*)d_in[5];
    const float* W2   = (const float*)d_in[6];
    const float* b2   = (const float*)d_in[7];
    const float* W3   = (const float*)d_in[8];
    const float* b3   = (const float*)d_in[9];
    float* out = (float*)d_out;

    const int IN_C = 256, HID_C = 256, OUT_C = 64;
    const int n_nodes = in_sizes[0] / IN_C;
    const int n_edges = in_sizes[1];
    const int nb      = (n_nodes + NB_ROWS - 1) >> NB_SHIFT;   // row buckets (<= NB_MAX)

    // workspace, all chunks 16B-aligned
    char* wsp = (char*)d_ws;
    auto take = [&wsp](size_t bytes) {
        char* p = wsp;
        wsp += (bytes + 15) & ~(size_t)15;
        return p;
    };
    __hip_bfloat16* G  = (__hip_bfloat16*)take((size_t)n_nodes * HID_C * 2);
    __hip_bfloat16* H  = (__hip_bfloat16*)take((size_t)n_nodes * HID_C * 2);
    uint2* epk    = (uint2*)take((size_t)n_edges * 8);
    int*   srow   = (int*)take((size_t)n_edges * 4);
    uint2* epk8   = (uint2*)take((size_t)n_edges * 8);
    int*   bcnt   = (int*)take((size_t)NB_MAX * 4);
    int*   gcursor= (int*)take((size_t)NB_MAX * 4);
    int*   gstart = (int*)take((size_t)(NB_MAX + 1) * 4);
    int*   row_ptr= (int*)take((size_t)(n_nodes + 1) * 4);
    __hip_bfloat16* Wb1 = (__hip_bfloat16*)take((size_t)(HID_C * IN_C + HID_C * HID_C + OUT_C * HID_C) * 2);
    __hip_bfloat16* Wb2 = Wb1 + HID_C * IN_C;
    __hip_bfloat16* Wb3 = Wb2 + HID_C * HID_C;

    const dim3 blk(256);
    const int n1 = HID_C * IN_C, n2 = HID_C * HID_C, n3 = OUT_C * HID_C;
    const int cwb = ((n1 + n2 + n3) / 4 + 255) / 256;
    const int ebb = (n_edges + EPB - 1) / EPB;
    const int rb  = (n_nodes + 3) / 4;            // spmm: 4 rows (waves) per block
    const int g_w = (n_nodes + 63) / 64;          // wide GEMM grid
    const int g_n = (n_nodes + 255) / 256;        // narrow GEMM grid

    // ---- weight convert + CSR build ----
    convw_kernel<<<cwb, blk, 0, stream>>>(W1, W2, W3, Wb1, n1, n2, n3);
    zero_bcnt_kernel<<<1, NB_MAX, 0, stream>>>(bcnt);
    histb_kernel<<<ebb, blk, 0, stream>>>(erow, bcnt, n_edges, nb);
    scanb_kernel<<<1, 256, 0, stream>>>(bcnt, gcursor, gstart, nb, n_edges);
    bin_pass_a<<<ebb, blk, 0, stream>>>(erow, ecol, eval, gcursor, srow, epk8, n_edges, nb);
    histr2_kernel<<<nb, blk, 0, stream>>>(gstart, srow, row_ptr, n_nodes, nb);
    bin_pass_b2<<<nb, blk, 0, stream>>>(gstart, srow, epk8, row_ptr, epk, n_nodes);

    // Layer 1: G = x @ W1^T + b1 ; H = relu(spmm(G))
    gemm_mfma_kernel<float><<<g_w, blk, 0, stream>>>(x, Wb1, b1, G, n_nodes, HID_C);
    spmm_csr256_kernel<true><<<rb, blk, 0, stream>>>(row_ptr, epk,
                                                     (const unsigned int*)G, H, n_nodes);

    // Layer 2: G = H @ W2^T + b2 ; H = relu(spmm(G))
    gemm_mfma_kernel<__hip_bfloat16><<<g_w, blk, 0, stream>>>(H, Wb2, b2, G, n_nodes, HID_C);
    spmm_csr256_kernel<true><<<rb, blk, 0, stream>>>(row_ptr, epk,
                                                     (const unsigned int*)G, H, n_nodes);

    // Layer 3: G[:, :64] = H @ W3^T + b3 ; out = spmm(G)
    gemm_mfma_kernel<__hip_bfloat16><<<g_n, blk, 0, stream>>>(H, Wb3, b3, G, n_nodes, OUT_C);
    spmm_csr64_kernel<<<rb, blk, 0, stream>>>(row_ptr, epk, G, out, n_nodes);
}

// Round 7
// 1018.397 us; speedup vs baseline: 2.0438x; 1.0043x over previous
//
#include <hip/hip_runtime.h>
#include <hip/hip_bf16.h>
#include <type_traits>

typedef short bf16x8 __attribute__((ext_vector_type(8)));
typedef float f32x4 __attribute__((ext_vector_type(4)));

union PkAB { bf16x8 v; __hip_bfloat16 h[8]; };
union PkO  { uint2 u;  __hip_bfloat16 h[4]; };

#define NB_SHIFT 9      // bucket = row >> 9 (512 rows/bucket)
#define NB_ROWS  512
#define NB_MAX   256    // max row-buckets
#define EPB      8192   // edges per block in binning kernels (32/thread)

// ---------------- weight convert (+ bcnt zero folded in) ----------------

__global__ __launch_bounds__(256) void convw_kernel(
    const float* __restrict__ W1, const float* __restrict__ W2,
    const float* __restrict__ W3, __hip_bfloat16* __restrict__ Wb,
    int* __restrict__ bcnt, int n1, int n2, int n3)
{
    if (blockIdx.x == 0) bcnt[threadIdx.x] = 0;   // NB_MAX == blockDim
    int i = (blockIdx.x * blockDim.x + threadIdx.x) * 4;
    if (i >= n1 + n2 + n3) return;
    const float* src; int off;
    if (i < n1)           { src = W1; off = i; }
    else if (i < n1 + n2) { src = W2; off = i - n1; }
    else                  { src = W3; off = i - n1 - n2; }
    const float4 v = *reinterpret_cast<const float4*>(src + off);
    PkO pk;
    pk.h[0] = __float2bfloat16(v.x); pk.h[1] = __float2bfloat16(v.y);
    pk.h[2] = __float2bfloat16(v.z); pk.h[3] = __float2bfloat16(v.w);
    *reinterpret_cast<uint2*>(Wb + i) = pk.u;
}

// ---------------- CSR build (binned, atomic-light, no global row scan) ------
// histb (bucket hist, LDS) -> scanb (bucket scan -> gstart/gcursor)
// -> bin_pass_a (bucket bin) -> histscat (per-bucket: row hist + LDS scan ->
// row_ptr + LDS-cursor scatter to final CSR order; zero global atomics)

__global__ __launch_bounds__(256) void histb_kernel(
    const int* __restrict__ erow, int* __restrict__ bcnt, int n_edges, int nb)
{
    __shared__ int lb[NB_MAX];
    const int tid = threadIdx.x;
    if (tid < NB_MAX) lb[tid] = 0;
    __syncthreads();
    const int e0 = blockIdx.x * EPB;
#pragma unroll
    for (int k = 0; k < 32; ++k) {
        const int e = e0 + tid + k * 256;
        if (e < n_edges) atomicAdd(&lb[erow[e] >> NB_SHIFT], 1);
    }
    __syncthreads();
    if (tid < nb && lb[tid]) atomicAdd(&bcnt[tid], lb[tid]);
}

// tiny bucket exclusive scan -> gcursor (pass_a alloc) + gstart (bucket ranges)
__global__ __launch_bounds__(256) void scanb_kernel(
    const int* __restrict__ bcnt, int* __restrict__ gcursor,
    int* __restrict__ gstart, int nb, int n_edges)
{
    __shared__ int sb[NB_MAX];
    const int tid = threadIdx.x;
    if (tid < nb) sb[tid] = bcnt[tid];
    __syncthreads();
    if (tid == 0) {
        int run = 0;
        for (int b = 0; b < nb; ++b) { const int t = sb[b]; sb[b] = run; run += t; }
    }
    __syncthreads();
    if (tid < nb) { gcursor[tid] = sb[tid]; gstart[tid] = sb[tid]; }
    if (tid == 0) gstart[nb] = n_edges;
}

// pass A: bucket-bin edges; per-block contiguous range per bucket.
__global__ __launch_bounds__(256) void bin_pass_a(
    const int* __restrict__ erow, const int* __restrict__ ecol,
    const float* __restrict__ eval, int* __restrict__ gcursor,
    int* __restrict__ srow, uint2* __restrict__ epk8, int n_edges, int nb)
{
    __shared__ int cnt[NB_MAX];
    __shared__ int base_s[NB_MAX];
    __shared__ int lcur[NB_MAX];
    const int tid = threadIdx.x;
    if (tid < NB_MAX) { cnt[tid] = 0; lcur[tid] = 0; }
    __syncthreads();
    const int e0 = blockIdx.x * EPB;
    int r[32];
#pragma unroll
    for (int k = 0; k < 32; ++k) {
        const int e = e0 + tid + k * 256;
        r[k] = -1;
        if (e < n_edges) { r[k] = erow[e]; atomicAdd(&cnt[r[k] >> NB_SHIFT], 1); }
    }
    __syncthreads();
    if (tid < nb && cnt[tid] > 0) base_s[tid] = atomicAdd(&gcursor[tid], cnt[tid]);
    __syncthreads();
#pragma unroll
    for (int k = 0; k < 32; ++k) {
        const int e = e0 + tid + k * 256;
        if (e < n_edges) {
            const int b = r[k] >> NB_SHIFT;
            const int pos = base_s[b] + atomicAdd(&lcur[b], 1);
            srow[pos] = r[k];
            uint2 rec;
            rec.x = (unsigned)ecol[e];
            rec.y = __float_as_uint(eval[e]);
            epk8[pos] = rec;
        }
    }
}

// fused per-bucket: row histogram + LDS exclusive scan -> row_ptr, then
// LDS-cursor scatter of the bucket's edges into final CSR order.
// gstart[b] (edges in buckets < b) is the global prefix at the bucket start.
__global__ __launch_bounds__(256) void histscat_kernel(
    const int* __restrict__ gstart, const int* __restrict__ srow,
    const uint2* __restrict__ epk8, int* __restrict__ row_ptr,
    uint2* __restrict__ epk, int n_nodes, int nb)
{
    __shared__ int h[NB_ROWS];    // hist, then reused as cursor
    __shared__ int hs[NB_ROWS];   // inclusive scan
    const int b = blockIdx.x;
    const int tid = threadIdx.x;
    h[tid] = 0; h[tid + 256] = 0;
    __syncthreads();
    const int lo = gstart[b], hi = gstart[b + 1];
    for (int i = lo + tid; i < hi; i += 256)
        atomicAdd(&h[srow[i] & (NB_ROWS - 1)], 1);
    __syncthreads();
    hs[tid] = h[tid]; hs[tid + 256] = h[tid + 256];
    __syncthreads();
    // inclusive Hillis-Steele over 512 entries (2 per thread)
    for (int off = 1; off < NB_ROWS; off <<= 1) {
        const int j0 = tid, j1 = tid + 256;
        const int a0 = (j0 >= off) ? hs[j0 - off] : 0;
        const int a1 = (j1 >= off) ? hs[j1 - off] : 0;
        __syncthreads();
        hs[j0] += a0; hs[j1] += a1;
        __syncthreads();
    }
    const int rowbase = b << NB_SHIFT;
#pragma unroll
    for (int s = 0; s < 2; ++s) {
        const int j = tid + s * 256;
        const int start = lo + hs[j] - h[j];    // exclusive prefix
        const int r = rowbase + j;
        if (r < n_nodes) row_ptr[r] = start;
        h[j] = start;                            // reuse as cursor
    }
    if (b == nb - 1 && tid == 0) row_ptr[n_nodes] = gstart[nb];
    __syncthreads();
    // scatter (rows bucket-exclusive -> LDS atomics only)
    int i = lo + tid;
    for (; i + 768 < hi; i += 1024) {
        const int r0 = srow[i];
        const int r1 = srow[i + 256];
        const int r2 = srow[i + 512];
        const int r3 = srow[i + 768];
        const uint2 e0 = epk8[i];
        const uint2 e1 = epk8[i + 256];
        const uint2 e2 = epk8[i + 512];
        const uint2 e3 = epk8[i + 768];
        epk[atomicAdd(&h[r0 & (NB_ROWS - 1)], 1)] = e0;
        epk[atomicAdd(&h[r1 & (NB_ROWS - 1)], 1)] = e1;
        epk[atomicAdd(&h[r2 & (NB_ROWS - 1)], 1)] = e2;
        epk[atomicAdd(&h[r3 & (NB_ROWS - 1)], 1)] = e3;
    }
    for (; i < hi; i += 256) {
        const int r = srow[i];
        epk[atomicAdd(&h[r & (NB_ROWS - 1)], 1)] = epk8[i];
    }
}

// ---------------- MFMA GEMM: Y_bf16[M,N] = X[M,256] @ Wb[N,256]^T + b ----------------

template<typename TIN>
__device__ __forceinline__ bf16x8 load_frag(const TIN* __restrict__ p) {
    if constexpr (std::is_same<TIN, float>::value) {
        const float4 lo = *reinterpret_cast<const float4*>(p);
        const float4 hi = *reinterpret_cast<const float4*>(p + 4);
        PkAB pk;
        pk.h[0] = __float2bfloat16(lo.x); pk.h[1] = __float2bfloat16(lo.y);
        pk.h[2] = __float2bfloat16(lo.z); pk.h[3] = __float2bfloat16(lo.w);
        pk.h[4] = __float2bfloat16(hi.x); pk.h[5] = __float2bfloat16(hi.y);
        pk.h[6] = __float2bfloat16(hi.z); pk.h[7] = __float2bfloat16(hi.w);
        return pk.v;
    } else {
        return *reinterpret_cast<const bf16x8*>(p);
    }
}

template<typename TIN>
__global__ __launch_bounds__(256) void gemm_mfma_kernel(
    const TIN* __restrict__ X,
    const __hip_bfloat16* __restrict__ Wb,   // [N,256] bf16
    const float* __restrict__ bias,
    __hip_bfloat16* __restrict__ Y,
    int M, int N)
{
    constexpr int K = 256;
    const int tid  = threadIdx.x;
    const int lane = tid & 63;
    const int w    = tid >> 6;
    const int quad = lane >> 4;
    const int l16  = lane & 15;
    const bool wide = (N == 256);
    const int m0 = blockIdx.x * (wide ? 64 : 256) + (wide ? 0 : w * 64);
    const int n0 = wide ? w * 64 : 0;

    int mr[4];
#pragma unroll
    for (int mt = 0; mt < 4; ++mt) {
        const int r = m0 + mt * 16 + l16;
        mr[mt] = (r < M) ? r : (M - 1);   // clamped read; store guarded
    }
    const __hip_bfloat16* wp = Wb + (size_t)(n0 + l16) * K + quad * 8;

    f32x4 acc[4][4] = {};
    bf16x8 a_cur[4], b_cur[4];
#pragma unroll
    for (int mt = 0; mt < 4; ++mt)
        a_cur[mt] = load_frag(X + (size_t)mr[mt] * K + quad * 8);
#pragma unroll
    for (int nt = 0; nt < 4; ++nt)
        b_cur[nt] = *reinterpret_cast<const bf16x8*>(wp + nt * 16 * K);

#pragma unroll
    for (int ks = 0; ks < 8; ++ks) {
        bf16x8 a_nxt[4], b_nxt[4];
        if (ks < 7) {
            const int ko = (ks + 1) * 32 + quad * 8;
#pragma unroll
            for (int mt = 0; mt < 4; ++mt)
                a_nxt[mt] = load_frag(X + (size_t)mr[mt] * K + ko);
#pragma unroll
            for (int nt = 0; nt < 4; ++nt)
                b_nxt[nt] = *reinterpret_cast<const bf16x8*>(wp + nt * 16 * K + (ks + 1) * 32);
        }
#pragma unroll
        for (int mt = 0; mt < 4; ++mt)
#pragma unroll
            for (int nt = 0; nt < 4; ++nt)
                acc[mt][nt] = __builtin_amdgcn_mfma_f32_16x16x32_bf16(
                    a_cur[mt], b_cur[nt], acc[mt][nt], 0, 0, 0);
        if (ks < 7) {
#pragma unroll
            for (int mt = 0; mt < 4; ++mt) a_cur[mt] = a_nxt[mt];
#pragma unroll
            for (int nt = 0; nt < 4; ++nt) b_cur[nt] = b_nxt[nt];
        }
    }

    float bv[4];
#pragma unroll
    for (int nt = 0; nt < 4; ++nt) bv[nt] = bias[n0 + nt * 16 + l16];
#pragma unroll
    for (int mt = 0; mt < 4; ++mt)
#pragma unroll
        for (int r = 0; r < 4; ++r) {
            const int row = m0 + mt * 16 + quad * 4 + r;
            if (row < M) {
#pragma unroll
                for (int nt = 0; nt < 4; ++nt)
                    Y[(size_t)row * N + n0 + nt * 16 + l16] =
                        __float2bfloat16(acc[mt][nt][r] + bv[nt]);
            }
        }
}

// ---------------- CSR gather SpMM ----------------

// C=256: one wave per row, lane = 4 channels; 8 edges in flight; bf16 out (+relu).
// At the fabric random-line-rate roofline (~7.9 TB/s delivered, 217 us).
template<bool RELU>
__global__ __launch_bounds__(256) void spmm_csr256_kernel(
    const int* __restrict__ row_ptr,
    const uint2* __restrict__ epk,        // packed {col, val_bits}
    const unsigned int* __restrict__ H,   // bf16 pairs; row stride 128 uints
    __hip_bfloat16* __restrict__ out,     // row stride 256
    int n_nodes)
{
    const int row = blockIdx.x * 4 + (threadIdx.x >> 6);
    if (row >= n_nodes) return;
    const int lane = threadIdx.x & 63;
    const int cu = lane * 2;

    int p = row_ptr[row];
    const int end = row_ptr[row + 1];

    float a0 = 0.f, a1 = 0.f, a2 = 0.f, a3 = 0.f;
    union { unsigned int i; float f; } t;

#define ACC_EDGE(u, v)                                        \
    t.i = (u).x << 16;          a0 = fmaf((v), t.f, a0);      \
    t.i = (u).x & 0xffff0000u;  a1 = fmaf((v), t.f, a1);      \
    t.i = (u).y << 16;          a2 = fmaf((v), t.f, a2);      \
    t.i = (u).y & 0xffff0000u;  a3 = fmaf((v), t.f, a3);

    for (; p + 7 < end; p += 8) {
        uint2 r[8];
#pragma unroll
        for (int j = 0; j < 8; ++j) r[j] = epk[p + j];
        uint2 u[8];
#pragma unroll
        for (int j = 0; j < 8; ++j)
            u[j] = *reinterpret_cast<const uint2*>(H + (size_t)r[j].x * 128 + cu);
#pragma unroll
        for (int j = 0; j < 8; ++j) { ACC_EDGE(u[j], __uint_as_float(r[j].y)) }
    }
    for (; p < end; ++p) {
        const uint2 r = epk[p];
        const uint2 u = *reinterpret_cast<const uint2*>(H + (size_t)r.x * 128 + cu);
        ACC_EDGE(u, __uint_as_float(r.y))
    }
#undef ACC_EDGE

    if (RELU) {
        a0 = fmaxf(a0, 0.f); a1 = fmaxf(a1, 0.f);
        a2 = fmaxf(a2, 0.f); a3 = fmaxf(a3, 0.f);
    }
    PkO pk;
    pk.h[0] = __float2bfloat16(a0); pk.h[1] = __float2bfloat16(a1);
    pk.h[2] = __float2bfloat16(a2); pk.h[3] = __float2bfloat16(a3);
    *reinterpret_cast<uint2*>(out + (size_t)row * 256 + lane * 4) = pk.u;
}

// C=64: one wave per row; half-wave per edge (lane = 2 channels); 8 edges
// in flight per half; f32 out
__global__ __launch_bounds__(256) void spmm_csr64_kernel(
    const int* __restrict__ row_ptr,
    const uint2* __restrict__ epk,
    const __hip_bfloat16* __restrict__ H,  // row stride 64
    float* __restrict__ out, int n_nodes)
{
    const int row = blockIdx.x * 4 + (threadIdx.x >> 6);
    if (row >= n_nodes) return;
    const int lane = threadIdx.x & 63;
    const int half = lane >> 5;
    const int sl   = lane & 31;

    const int end = row_ptr[row + 1];
    int p = row_ptr[row] + half;

    float a0 = 0.f, a1 = 0.f;
    union { unsigned int i; float f; } t;

#define ACC_E64(u, v)                                    \
    t.i = (u) << 16;          a0 = fmaf((v), t.f, a0);   \
    t.i = (u) & 0xffff0000u;  a1 = fmaf((v), t.f, a1);

    for (; p + 14 < end; p += 16) {   // this half handles p, p+2, ..., p+14
        uint2 r[8];
#pragma unroll
        for (int j = 0; j < 8; ++j) r[j] = epk[p + 2 * j];
        unsigned int u[8];
#pragma unroll
        for (int j = 0; j < 8; ++j)
            u[j] = *reinterpret_cast<const unsigned int*>(H + (size_t)r[j].x * 64 + sl * 2);
#pragma unroll
        for (int j = 0; j < 8; ++j) { ACC_E64(u[j], __uint_as_float(r[j].y)) }
    }
    for (; p < end; p += 2) {
        const uint2 r = epk[p];
        const unsigned int u = *reinterpret_cast<const unsigned int*>(H + (size_t)r.x * 64 + sl * 2);
        ACC_E64(u, __uint_as_float(r.y))
    }
#undef ACC_E64

    a0 += __shfl_down(a0, 32, 64);
    a1 += __shfl_down(a1, 32, 64);
    if (half == 0)
        *reinterpret_cast<float2*>(out + (size_t)row * 64 + sl * 2) = make_float2(a0, a1);
}

// ---------------- launch ----------------

extern "C" void kernel_launch(void* const* d_in, const int* in_sizes, int n_in,
                              void* d_out, int out_size, void* d_ws, size_t ws_size,
                              hipStream_t stream)
{
    const float* x    = (const float*)d_in[0];
    const int*   erow = (const int*)  d_in[1];
    const int*   ecol = (const int*)  d_in[2];
    const float* eval = (const float*)d_in[3];
    const float* W1   = (const float*)d_in[4];
    const float* b1   = (const float*)d_in[5];
    const float* W2   = (const float*)d_in[6];
    const float* b2   = (const float*)d_in[7];
    const float* W3   = (const float*)d_in[8];
    const float* b3   = (const float*)d_in[9];
    float* out = (float*)d_out;

    const int IN_C = 256, HID_C = 256, OUT_C = 64;
    const int n_nodes = in_sizes[0] / IN_C;
    const int n_edges = in_sizes[1];
    const int nb      = (n_nodes + NB_ROWS - 1) >> NB_SHIFT;   // row buckets (<= NB_MAX)

    // workspace, all chunks 16B-aligned
    char* wsp = (char*)d_ws;
    auto take = [&wsp](size_t bytes) {
        char* p = wsp;
        wsp += (bytes + 15) & ~(size_t)15;
        return p;
    };
    __hip_bfloat16* G  = (__hip_bfloat16*)take((size_t)n_nodes * HID_C * 2);
    __hip_bfloat16* H  = (__hip_bfloat16*)take((size_t)n_nodes * HID_C * 2);
    uint2* epk    = (uint2*)take((size_t)n_edges * 8);
    int*   srow   = (int*)take((size_t)n_edges * 4);
    uint2* epk8   = (uint2*)take((size_t)n_edges * 8);
    int*   bcnt   = (int*)take((size_t)NB_MAX * 4);
    int*   gcursor= (int*)take((size_t)NB_MAX * 4);
    int*   gstart = (int*)take((size_t)(NB_MAX + 1) * 4);
    int*   row_ptr= (int*)take((size_t)(n_nodes + 1) * 4);
    __hip_bfloat16* Wb1 = (__hip_bfloat16*)take((size_t)(HID_C * IN_C + HID_C * HID_C + OUT_C * HID_C) * 2);
    __hip_bfloat16* Wb2 = Wb1 + HID_C * IN_C;
    __hip_bfloat16* Wb3 = Wb2 + HID_C * HID_C;

    const dim3 blk(256);
    const int n1 = HID_C * IN_C, n2 = HID_C * HID_C, n3 = OUT_C * HID_C;
    const int cwb = ((n1 + n2 + n3) / 4 + 255) / 256;
    const int ebb = (n_edges + EPB - 1) / EPB;
    const int rb  = (n_nodes + 3) / 4;            // spmm: 4 rows (waves) per block
    const int g_w = (n_nodes + 63) / 64;          // wide GEMM grid
    const int g_n = (n_nodes + 255) / 256;        // narrow GEMM grid

    // ---- weight convert (+bcnt zero) + CSR build ----
    convw_kernel<<<cwb, blk, 0, stream>>>(W1, W2, W3, Wb1, bcnt, n1, n2, n3);
    histb_kernel<<<ebb, blk, 0, stream>>>(erow, bcnt, n_edges, nb);
    scanb_kernel<<<1, 256, 0, stream>>>(bcnt, gcursor, gstart, nb, n_edges);
    bin_pass_a<<<ebb, blk, 0, stream>>>(erow, ecol, eval, gcursor, srow, epk8, n_edges, nb);
    histscat_kernel<<<nb, blk, 0, stream>>>(gstart, srow, epk8, row_ptr, epk, n_nodes, nb);

    // Layer 1: G = x @ W1^T + b1 ; H = relu(spmm(G))
    gemm_mfma_kernel<float><<<g_w, blk, 0, stream>>>(x, Wb1, b1, G, n_nodes, HID_C);
    spmm_csr256_kernel<true><<<rb, blk, 0, stream>>>(row_ptr, epk,
                                                     (const unsigned int*)G, H, n_nodes);

    // Layer 2: G = H @ W2^T + b2 ; H = relu(spmm(G))
    gemm_mfma_kernel<__hip_bfloat16><<<g_w, blk, 0, stream>>>(H, Wb2, b2, G, n_nodes, HID_C);
    spmm_csr256_kernel<true><<<rb, blk, 0, stream>>>(row_ptr, epk,
                                                     (const unsigned int*)G, H, n_nodes);

    // Layer 3: G[:, :64] = H @ W3^T + b3 ; out = spmm(G)
    gemm_mfma_kernel<__hip_bfloat16><<<g_n, blk, 0, stream>>>(H, Wb3, b3, G, n_nodes, OUT_C);
    spmm_csr64_kernel<<<rb, blk, 0, stream>>>(row_ptr, epk, G, out, n_nodes);
}